// Round 3
// baseline (747.323 us; speedup 1.0000x reference)
//
#include <hip/hip_runtime.h>
#include <cstddef>
#include <cstdint>

#define NN   8
#define CIN  1024
#define PL   256
#define PE   1024
#define HW   4096
#define EPS_ 1e-5f

typedef _Float16 half8 __attribute__((ext_vector_type(8)));
typedef float floatx4 __attribute__((ext_vector_type(4)));

union HU { uint4 u4; half8 h8; };

__device__ inline uint32_t pack2(float v) {
  union { _Float16 f[2]; uint32_t u; } z;
  _Float16 h = (_Float16)v;
  z.f[0] = h;
  z.f[1] = (_Float16)(v - (float)h);
  return z.u;
}

// Output tail offsets (float offsets in d_out)
static const size_t OFF1 = 33554432;
static const size_t OFF2 = OFF1 + 18;
static const size_t OFF3 = OFF2 + 27;

// ============ prep: weight frag-shuffles + bn fold + zero pooled/vec2 ====
// A-fragment layout (16x16x32 f16): frag f holds rows p0f..p0f+15, k c0f..c0f+31.
// addr(halfs) = f*1024 + hilo*512 + lane*8 + e, lane = ((c&31)>>3)*16 + (p&15).
// w1f: f = kc*16 + pb          (kc<32, pb<16)
// w3f: f = kc*64 + pb          (kc<8,  pb<64)
// w2f: f = (tap*8+kc)*16 + pb  (tap<9, kc<8, pb<16)
__global__ __launch_bounds__(256) void k_prep(
    const float* __restrict__ bn1, const float* __restrict__ bn2,
    const float* __restrict__ bn3, const float* __restrict__ w1,
    const float* __restrict__ w2, const float* __restrict__ w3,
    _Float16* __restrict__ w1f, _Float16* __restrict__ w2f,
    _Float16* __restrict__ w3f,
    float* __restrict__ s1, float* __restrict__ t1,
    float* __restrict__ s2, float* __restrict__ t2,
    float* __restrict__ s3, float* __restrict__ t3,
    float* __restrict__ pooled, float* __restrict__ vec2) {
  unsigned idx = blockIdx.x * 256 + threadIdx.x;
  if (idx < 262144u) {
    int p = idx >> 10, c = idx & 1023;
    float v = w1[idx]; _Float16 h = (_Float16)v;
    int lane = (((c & 31) >> 3) << 4) | (p & 15);
    size_t base = (size_t)(((c >> 5) * 16 + (p >> 4))) * 1024 + lane * 8 + (c & 7);
    w1f[base] = h; w1f[base + 512] = (_Float16)(v - (float)h);
  } else if (idx < 524288u) {
    unsigned i = idx - 262144u;
    int p = i >> 8, c = i & 255;
    float v = w3[i]; _Float16 h = (_Float16)v;
    int lane = (((c & 31) >> 3) << 4) | (p & 15);
    size_t base = (size_t)((c >> 5) * 64 + (p >> 4)) * 1024 + lane * 8 + (c & 7);
    w3f[base] = h; w3f[base + 512] = (_Float16)(v - (float)h);
  } else if (idx < 1114112u) {
    unsigned i = idx - 524288u;
    unsigned p = i / 2304u, rem = i - p * 2304u;
    unsigned c = rem / 9u, tap = rem - c * 9u;
    float v = w2[i]; _Float16 h = (_Float16)v;
    int lane = (((c & 31) >> 3) << 4) | (p & 15);
    size_t base = (size_t)((tap * 8 + (c >> 5)) * 16 + (p >> 4)) * 1024 + lane * 8 + (c & 7);
    w2f[base] = h; w2f[base + 512] = (_Float16)(v - (float)h);
  } else if (idx < 1638400u) {
    pooled[idx - 1114112u] = 0.f;
  } else if (idx < 1640448u) {
    vec2[idx - 1638400u] = 0.f;
  } else if (idx < 1641984u) {
    int i = idx - 1640448u;
    if (i < 256) {
      float g = bn1[i], b = bn1[256 + i], m = bn1[512 + i], v = bn1[768 + i];
      float s = g / sqrtf(v + EPS_);
      s1[i] = s; t1[i] = b - m * s;
    } else if (i < 512) {
      int c = i - 256;
      float g = bn2[c], b = bn2[256 + c], m = bn2[512 + c], v = bn2[768 + c];
      float s = g / sqrtf(v + EPS_);
      s2[c] = s; t2[c] = b - m * s;
    } else {
      int c = i - 512;
      float g = bn3[c], b = bn3[1024 + c], m = bn3[2048 + c], v = bn3[3072 + c];
      float s = g / sqrtf(v + EPS_);
      s3[c] = s; t3[c] = b - m * s;
    }
  }
}

// ============ x -> transposed fp16 hi/lo split + fused 8x8 pooling =======
__global__ __launch_bounds__(256) void k_xsplit(const float* __restrict__ x,
                                                _Float16* __restrict__ xh,
                                                _Float16* __restrict__ xl,
                                                float* __restrict__ pooled) {
  const int bx = blockIdx.x;  // image row 0..63
  const int hw0 = bx * 64, c0 = blockIdx.y * 64, n = blockIdx.z;
  const int t = threadIdx.x;
  __shared__ float Tt[64][65];
#pragma unroll
  for (int j = 0; j < 4; ++j) {
    int rc = (t >> 4) + j * 16;
    int col = (t & 15) * 4;
    float4 v = *(const float4*)(x + ((size_t)(n * 1024) + c0 + rc) * 4096 + hw0 + col);
    Tt[col + 0][rc] = v.x; Tt[col + 1][rc] = v.y;
    Tt[col + 2][rc] = v.z; Tt[col + 3][rc] = v.w;
  }
  __syncthreads();
  // pooling partial sums (cell row = bx>>3, 8 cell cols)
  {
    const int ch = t & 63, grp = t >> 6;
    const int pr = bx >> 3;
#pragma unroll
    for (int cc = 0; cc < 2; ++cc) {
      int pc = grp * 2 + cc;
      float s = 0.f;
#pragma unroll
      for (int px = 0; px < 8; ++px) s += Tt[pc * 8 + px][ch];
      atomicAdd(&pooled[(size_t)(n * 64 + pr * 8 + pc) * 1024 + c0 + ch], s * (1.f / 64.f));
    }
  }
  const int hwl = t >> 2, part = t & 3;
  size_t ob = ((size_t)(n * 4096) + hw0 + hwl) * 1024 + c0 + part * 16;
#pragma unroll
  for (int k2 = 0; k2 < 2; ++k2) {
    half8 vh, vl;
#pragma unroll
    for (int e = 0; e < 8; ++e) {
      float v = Tt[hwl][part * 16 + k2 * 8 + e];
      _Float16 hh = (_Float16)v;
      vh[e] = hh; vl[e] = (_Float16)(v - (float)hh);
    }
    *(half8*)(xh + ob + k2 * 8) = vh;
    *(half8*)(xl + ob + k2 * 8) = vl;
  }
}

// ============ vec1 from pooled ===========================================
__global__ __launch_bounds__(256) void k_vec1(const float* __restrict__ pooled,
                                              float* __restrict__ vec1) {
  const int n = blockIdx.x, t = threadIdx.x;
#pragma unroll
  for (int j = 0; j < 4; ++j) {
    int c = j * 256 + t;
    float s = 0.f;
    for (int cell = 0; cell < 64; ++cell)
      s += pooled[(size_t)(n * 64 + cell) * 1024 + c];
    vec1[n * 1024 + c] = s * (1.f / 64.f);
  }
}

// ============ spatial mask ===============================================
__global__ __launch_bounds__(256) void k_masks(const float* __restrict__ wsconv,
                                               const float* __restrict__ wsbias,
                                               const float* __restrict__ pooled,
                                               float* __restrict__ masks) {
  const int bid = blockIdx.x;
  const int n = bid >> 6, cell = bid & 63, ph = cell >> 3, pw = cell & 7;
  const int tid = threadIdx.x;
  const float* pl = pooled + (size_t)n * 64 * 1024;
  float acc = 0.f;
#pragma unroll
  for (int kh = 0; kh < 3; ++kh) {
    int py = ph + kh - 1;
    if (py < 0 || py > 7) continue;
#pragma unroll
    for (int kw = 0; kw < 3; ++kw) {
      int px = pw + kw - 1;
      if (px < 0 || px > 7) continue;
      float4 pv = *(const float4*)(pl + (size_t)(py * 8 + px) * 1024 + tid * 4);
      int k = kh * 3 + kw;
      acc += pv.x * wsconv[(tid * 4 + 0) * 9 + k] + pv.y * wsconv[(tid * 4 + 1) * 9 + k]
           + pv.z * wsconv[(tid * 4 + 2) * 9 + k] + pv.w * wsconv[(tid * 4 + 3) * 9 + k];
    }
  }
  __shared__ float red[256];
  red[tid] = acc;
  __syncthreads();
  for (int s = 128; s > 0; s >>= 1) {
    if (tid < s) red[tid] += red[tid + s];
    __syncthreads();
  }
  if (tid == 0) masks[n * 64 + cell] = (red[0] + wsbias[0] >= 0.f) ? 1.f : 0.f;
}

// ============ mc1 ========================================================
__global__ __launch_bounds__(64) void k_mc1(const float* __restrict__ wc1,
                                            const float* __restrict__ bc1,
                                            const float* __restrict__ vec1,
                                            float* __restrict__ mc1) {
  const int bx = blockIdx.x;
  const int n = bx >> 8, p = bx & 255;
  const int t = threadIdx.x;
  const float* v = vec1 + n * 1024;
  const float* wr = wc1 + (size_t)p * 1024;
  float acc = 0.f;
#pragma unroll
  for (int j = 0; j < 16; ++j) acc += v[t + 64 * j] * wr[t + 64 * j];
  for (int m = 1; m < 64; m <<= 1) acc += __shfl_xor(acc, m, 64);
  if (t == 0) mc1[n * 256 + p] = (acc + bc1[p] >= 0.f) ? 1.f : 0.f;
}

// ============ conv1: MFMA GEMM, A-frags direct from global ===============
__global__ __launch_bounds__(256) void k_gemm1(
    const _Float16* __restrict__ xh, const _Float16* __restrict__ xl,
    const _Float16* __restrict__ w1f,
    const float* __restrict__ s1, const float* __restrict__ t1,
    const float* __restrict__ mc1, const float* __restrict__ masks,
    _Float16* __restrict__ o1h, _Float16* __restrict__ o1l) {
  const int hw0 = blockIdx.x * 128, p0 = blockIdx.y * 128, n = blockIdx.z;
  const int t = threadIdx.x;
  const int lane = t & 63, w = t >> 6;
  const int l15 = lane & 15, l4 = lane >> 4;
  const int wr = w >> 1, wc = w & 1;
  __shared__ __align__(16) char smem[33792];
  _Float16* LB = (_Float16*)smem;  // Bh 0, Bl 5120 (halfs)
  floatx4 acc[4][4] = {};
  const size_t nb = (size_t)(n * 4096) + hw0;
  const _Float16* wfp = w1f + (size_t)((p0 >> 4) + wr * 4) * 1024 + lane * 8;
  for (int kc = 0; kc < 32; ++kc) {
    const int c0 = kc * 32;
    half8 tmp[4];
#pragma unroll
    for (int j = 0; j < 4; ++j) {
      int u = t + 256 * j;
      int kind = u >> 9, rem = u & 511, row = rem >> 2, q = rem & 3;
      const _Float16* src = (kind ? xl : xh) + (nb + row) * 1024 + c0 + q * 8;
      tmp[j] = *(const half8*)src;
    }
    half8 ah[4], al[4];
#pragma unroll
    for (int i = 0; i < 4; ++i) {
      const _Float16* ap = wfp + (size_t)(kc * 16 + i) * 1024;
      ah[i] = *(const half8*)ap;
      al[i] = *(const half8*)(ap + 512);
    }
    __syncthreads();
#pragma unroll
    for (int j = 0; j < 4; ++j) {
      int u = t + 256 * j;
      int kind = u >> 9, rem = u & 511, row = rem >> 2, q = rem & 3;
      *(half8*)(LB + kind * 5120 + row * 40 + q * 8) = tmp[j];
    }
    __syncthreads();
    half8 bh[4], bl[4];
#pragma unroll
    for (int j = 0; j < 4; ++j) {
      int r = (wc * 64 + j * 16 + l15) * 40 + l4 * 8;
      bh[j] = *(const half8*)(LB + r);
      bl[j] = *(const half8*)(LB + 5120 + r);
    }
#pragma unroll
    for (int i = 0; i < 4; ++i)
#pragma unroll
      for (int j = 0; j < 4; ++j) {
        acc[i][j] = __builtin_amdgcn_mfma_f32_16x16x32_f16(ah[i], bh[j], acc[i][j], 0, 0, 0);
        acc[i][j] = __builtin_amdgcn_mfma_f32_16x16x32_f16(ah[i], bl[j], acc[i][j], 0, 0, 0);
        acc[i][j] = __builtin_amdgcn_mfma_f32_16x16x32_f16(al[i], bh[j], acc[i][j], 0, 0, 0);
      }
  }
  uint32_t (*T)[132] = (uint32_t(*)[132])smem;
  const int n64 = n * 64;
  const float* mc1n = mc1 + n * 256;
  for (int h = 0; h < 2; ++h) {
    __syncthreads();
    if (wc == h) {
#pragma unroll
      for (int j = 0; j < 4; ++j) {
        int nl = j * 16 + l15;
        int pix = hw0 + h * 64 + nl;
        float msk = masks[n64 + ((pix >> 9) << 3) + ((pix & 63) >> 3)];
#pragma unroll
        for (int i = 0; i < 4; ++i) {
          uint32_t pk[4];
#pragma unroll
          for (int r = 0; r < 4; ++r) {
            int m = wr * 64 + i * 16 + l4 * 4 + r;
            int p = p0 + m;
            float val = fmaxf(fmaf(acc[i][j][r], s1[p], t1[p]), 0.f) * (mc1n[p] * msk);
            pk[r] = pack2(val);
          }
          *(uint4*)&T[nl][wr * 64 + i * 16 + l4 * 4] = *(uint4*)pk;
        }
      }
    }
    __syncthreads();
    {
      int row = t >> 2, seg = t & 3;
      int pix = hw0 + h * 64 + row;
      _Float16* dh = o1h + ((size_t)(n * 4096) + pix) * 256 + p0 + seg * 32;
      _Float16* dl = o1l + ((size_t)(n * 4096) + pix) * 256 + p0 + seg * 32;
#pragma unroll
      for (int k2 = 0; k2 < 4; ++k2) {
        uint4 a = *(uint4*)&T[row][seg * 32 + k2 * 8];
        uint4 b = *(uint4*)&T[row][seg * 32 + k2 * 8 + 4];
        uint4 hv = make_uint4((a.x & 0xFFFFu) | (a.y << 16), (a.z & 0xFFFFu) | (a.w << 16),
                              (b.x & 0xFFFFu) | (b.y << 16), (b.z & 0xFFFFu) | (b.w << 16));
        uint4 lv = make_uint4((a.x >> 16) | (a.y & 0xFFFF0000u), (a.z >> 16) | (a.w & 0xFFFF0000u),
                              (b.x >> 16) | (b.y & 0xFFFF0000u), (b.z >> 16) | (b.w & 0xFFFF0000u));
        *(uint4*)(dh + k2 * 8) = hv;
        *(uint4*)(dl + k2 * 8) = lv;
      }
    }
  }
}

// ============ vec2 =======================================================
__global__ __launch_bounds__(256) void k_vec2(const _Float16* __restrict__ o1h,
                                              const _Float16* __restrict__ o1l,
                                              float* __restrict__ vec2) {
  const int n = blockIdx.x >> 5, ch = blockIdx.x & 31;
  const int t = threadIdx.x;
  const _Float16* bh = o1h + ((size_t)(n * 4096) + ch * 128) * 256 + t;
  const _Float16* bl = o1l + ((size_t)(n * 4096) + ch * 128) * 256 + t;
  float s = 0.f;
  for (int i = 0; i < 128; ++i)
    s += (float)bh[(size_t)i * 256] + (float)bl[(size_t)i * 256];
  atomicAdd(&vec2[n * 256 + t], s * (1.f / 4096.f));
}

// ============ mc2 ========================================================
__global__ __launch_bounds__(64) void k_mc2(const float* __restrict__ wc2,
                                            const float* __restrict__ bc2,
                                            const float* __restrict__ vec2,
                                            float* __restrict__ mc2) {
  const int bx = blockIdx.x;
  const int n = bx >> 8, p = bx & 255;
  const int t = threadIdx.x;
  const float* v = vec2 + n * 256;
  const float* wr = wc2 + (size_t)p * 256;
  float acc = 0.f;
#pragma unroll
  for (int j = 0; j < 4; ++j) acc += v[t + 64 * j] * wr[t + 64 * j];
  for (int m = 1; m < 64; m <<= 1) acc += __shfl_xor(acc, m, 64);
  if (t == 0) mc2[n * 256 + p] = (acc + bc2[p] >= 0.f) ? 1.f : 0.f;
}

// ============ conv2: 3x3 MFMA, strip-only LDS, A-frags from global =======
__global__ __launch_bounds__(256) void k_gemm2(
    const _Float16* __restrict__ o1h, const _Float16* __restrict__ o1l,
    const _Float16* __restrict__ w2f,
    const float* __restrict__ s2, const float* __restrict__ t2,
    const float* __restrict__ mc2, const float* __restrict__ masks,
    _Float16* __restrict__ o2h, _Float16* __restrict__ o2l) {
  const int bt = blockIdx.x, p0 = blockIdx.y * 128, n = blockIdx.z;
  const int hw0 = bt * 128;
  const int t = threadIdx.x;
  const int lane = t & 63, w = t >> 6;
  const int l15 = lane & 15, l4 = lane >> 4;
  const int wr = w >> 1, wc = w & 1;
  // LDS: strip hi 0 (10560 halfs), lo 10560  -> 42240 B total
  __shared__ __align__(16) char smem[42240];
  _Float16* LB = (_Float16*)smem;
  floatx4 acc[4][4] = {};
  const size_t onb = (size_t)(n * 4096);
  const int row0 = bt * 2 - 1;
  const _Float16* wfp = w2f + (size_t)((p0 >> 4) + wr * 4) * 1024 + lane * 8;
  for (int kc = 0; kc < 8; ++kc) {
    const int c0 = kc * 32;
    HU st[9];
#pragma unroll
    for (int j2 = 0; j2 < 9; ++j2) {
      int u = t + 256 * j2;
      st[j2].u4 = make_uint4(0u, 0u, 0u, 0u);
      if (u < 2112) {
        int kind = (u >= 1056) ? 1 : 0;
        int rem = u - kind * 1056;
        int pix = rem >> 2, q = rem & 3;
        int sr = pix / 66, sc = pix - sr * 66;
        int gr = row0 + sr, gc = sc - 1;
        if (gr >= 0 && gr < 64 && gc >= 0 && gc < 64) {
          const _Float16* src = (kind ? o1l : o1h) + (onb + gr * 64 + gc) * 256 + c0 + q * 8;
          st[j2].h8 = *(const half8*)src;
        }
      }
    }
    __syncthreads();  // prior chunk's strip reads complete
#pragma unroll
    for (int j2 = 0; j2 < 9; ++j2) {
      int u = t + 256 * j2;
      if (u < 2112) {
        int kind = (u >= 1056) ? 1 : 0;
        int rem = u - kind * 1056;
        int pix = rem >> 2, q = rem & 3;
        *(half8*)(LB + kind * 10560 + pix * 40 + q * 8) = st[j2].h8;
      }
    }
    __syncthreads();
#pragma unroll 1
    for (int tap = 0; tap < 9; ++tap) {
      const int kh = tap / 3, kw = tap - kh * 3;
      half8 ah[4], al[4], bh[4], bl[4];
#pragma unroll
      for (int i = 0; i < 4; ++i) {
        const _Float16* ap = wfp + (size_t)(((tap * 8 + kc) * 16) + i) * 1024;
        ah[i] = *(const half8*)ap;
        al[i] = *(const half8*)(ap + 512);
      }
#pragma unroll
      for (int j = 0; j < 4; ++j) {
        int pi = (wc + kh) * 66 + j * 16 + l15 + kw;
        bh[j] = *(const half8*)(LB + pi * 40 + l4 * 8);
        bl[j] = *(const half8*)(LB + 10560 + pi * 40 + l4 * 8);
      }
#pragma unroll
      for (int i = 0; i < 4; ++i)
#pragma unroll
        for (int j = 0; j < 4; ++j) {
          acc[i][j] = __builtin_amdgcn_mfma_f32_16x16x32_f16(ah[i], bh[j], acc[i][j], 0, 0, 0);
          acc[i][j] = __builtin_amdgcn_mfma_f32_16x16x32_f16(ah[i], bl[j], acc[i][j], 0, 0, 0);
          acc[i][j] = __builtin_amdgcn_mfma_f32_16x16x32_f16(al[i], bh[j], acc[i][j], 0, 0, 0);
        }
    }
  }
  uint32_t (*T)[132] = (uint32_t(*)[132])smem;
  const int n64 = n * 64;
  const float* mc2n = mc2 + n * 256;
  for (int h = 0; h < 2; ++h) {
    __syncthreads();
    if (wc == h) {
#pragma unroll
      for (int j = 0; j < 4; ++j) {
        int nl = j * 16 + l15;
        int pix = hw0 + h * 64 + nl;
        float msk = masks[n64 + ((pix >> 9) << 3) + ((pix & 63) >> 3)];
#pragma unroll
        for (int i = 0; i < 4; ++i) {
          uint32_t pk[4];
#pragma unroll
          for (int r = 0; r < 4; ++r) {
            int m = wr * 64 + i * 16 + l4 * 4 + r;
            int p = p0 + m;
            float val = fmaxf(fmaf(acc[i][j][r], s2[p], t2[p]), 0.f) * (mc2n[p] * msk);
            pk[r] = pack2(val);
          }
          *(uint4*)&T[nl][wr * 64 + i * 16 + l4 * 4] = *(uint4*)pk;
        }
      }
    }
    __syncthreads();
    {
      int row = t >> 2, seg = t & 3;
      int pix = hw0 + h * 64 + row;
      _Float16* dh = o2h + ((size_t)(n * 4096) + pix) * 256 + p0 + seg * 32;
      _Float16* dl = o2l + ((size_t)(n * 4096) + pix) * 256 + p0 + seg * 32;
#pragma unroll
      for (int k2 = 0; k2 < 4; ++k2) {
        uint4 a = *(uint4*)&T[row][seg * 32 + k2 * 8];
        uint4 b = *(uint4*)&T[row][seg * 32 + k2 * 8 + 4];
        uint4 hv = make_uint4((a.x & 0xFFFFu) | (a.y << 16), (a.z & 0xFFFFu) | (a.w << 16),
                              (b.x & 0xFFFFu) | (b.y << 16), (b.z & 0xFFFFu) | (b.w << 16));
        uint4 lv = make_uint4((a.x >> 16) | (a.y & 0xFFFF0000u), (a.z >> 16) | (a.w & 0xFFFF0000u),
                              (b.x >> 16) | (b.y & 0xFFFF0000u), (b.z >> 16) | (b.w & 0xFFFF0000u));
        *(uint4*)(dh + k2 * 8) = hv;
        *(uint4*)(dl + k2 * 8) = lv;
      }
    }
  }
}

// ============ conv3: MFMA GEMM + bn3*mask + x + relu =====================
__global__ __launch_bounds__(256) void k_gemm3(
    const _Float16* __restrict__ o2h, const _Float16* __restrict__ o2l,
    const _Float16* __restrict__ w3f,
    const float* __restrict__ s3, const float* __restrict__ t3,
    const float* __restrict__ masks, const float* __restrict__ x,
    float* __restrict__ out) {
  const int hw0 = blockIdx.x * 128, p0 = blockIdx.y * 128, n = blockIdx.z;
  const int t = threadIdx.x;
  const int lane = t & 63, w = t >> 6;
  const int l15 = lane & 15, l4 = lane >> 4;
  const int wr = w >> 1, wc = w & 1;
  __shared__ __align__(16) char smem[20480];
  _Float16* LB = (_Float16*)smem;  // Bh 0, Bl 5120 (halfs)
  floatx4 acc[4][4] = {};
  const size_t nb = (size_t)(n * 4096) + hw0;
  const _Float16* wfp = w3f + (size_t)((p0 >> 4) + wr * 4) * 1024 + lane * 8;
  for (int kc = 0; kc < 8; ++kc) {
    const int c0 = kc * 32;
    half8 tmp[4];
#pragma unroll
    for (int j = 0; j < 4; ++j) {
      int u = t + 256 * j;
      int kind = u >> 9, rem = u & 511, row = rem >> 2, q = rem & 3;
      const _Float16* src = (kind ? o2l : o2h) + (nb + row) * 256 + c0 + q * 8;
      tmp[j] = *(const half8*)src;
    }
    half8 ah[4], al[4];
#pragma unroll
    for (int i = 0; i < 4; ++i) {
      const _Float16* ap = wfp + (size_t)(kc * 64 + i) * 1024;
      ah[i] = *(const half8*)ap;
      al[i] = *(const half8*)(ap + 512);
    }
    __syncthreads();
#pragma unroll
    for (int j = 0; j < 4; ++j) {
      int u = t + 256 * j;
      int kind = u >> 9, rem = u & 511, row = rem >> 2, q = rem & 3;
      *(half8*)(LB + kind * 5120 + row * 40 + q * 8) = tmp[j];
    }
    __syncthreads();
    half8 bh[4], bl[4];
#pragma unroll
    for (int j = 0; j < 4; ++j) {
      int r = (wc * 64 + j * 16 + l15) * 40 + l4 * 8;
      bh[j] = *(const half8*)(LB + r);
      bl[j] = *(const half8*)(LB + 5120 + r);
    }
#pragma unroll
    for (int i = 0; i < 4; ++i)
#pragma unroll
      for (int j = 0; j < 4; ++j) {
        acc[i][j] = __builtin_amdgcn_mfma_f32_16x16x32_f16(ah[i], bh[j], acc[i][j], 0, 0, 0);
        acc[i][j] = __builtin_amdgcn_mfma_f32_16x16x32_f16(ah[i], bl[j], acc[i][j], 0, 0, 0);
        acc[i][j] = __builtin_amdgcn_mfma_f32_16x16x32_f16(al[i], bh[j], acc[i][j], 0, 0, 0);
      }
    __syncthreads();
  }
  const int n64 = n * 64;
  float msk[4];
#pragma unroll
  for (int j = 0; j < 4; ++j) {
    int pix = hw0 + wc * 64 + j * 16 + l15;
    msk[j] = masks[n64 + ((pix >> 9) << 3) + ((pix & 63) >> 3)];
  }
#pragma unroll
  for (int i = 0; i < 4; ++i)
#pragma unroll
    for (int r = 0; r < 4; ++r) {
      int m = wr * 64 + i * 16 + l4 * 4 + r;
      int pe = p0 + m;
      float sc = s3[pe], sh = t3[pe];
      size_t rowoff = ((size_t)(n * 1024) + pe) * 4096 + hw0;
#pragma unroll
      for (int j = 0; j < 4; ++j) {
        int nl = wc * 64 + j * 16 + l15;
        float val = fmaf(acc[i][j][r], sc, sh) * msk[j];
        size_t off = rowoff + nl;
        out[off] = fmaxf(val + x[off], 0.f);
      }
    }
}

// ============ bookkeeping ================================================
__global__ __launch_bounds__(64) void k_book(const float* __restrict__ n1in,
                                             const float* __restrict__ n2in,
                                             const float* __restrict__ flin,
                                             const float* __restrict__ masks,
                                             const float* __restrict__ mc1,
                                             const float* __restrict__ mc2,
                                             float* __restrict__ out) {
  const int t = threadIdx.x;
  if (t < 9) {
    out[OFF1 + t] = n1in[t];
    out[OFF2 + t] = n2in[t];
    out[OFF3 + t] = flin[t];
  }
  if (t < 8) {
    float ns = 0.f, nc1 = 0.f, nc2 = 0.f;
    for (int i = 0; i < 64; ++i) ns += masks[t * 64 + i];
    for (int i = 0; i < 256; ++i) nc1 += mc1[t * 256 + i];
    for (int i = 0; i < 256; ++i) nc2 += mc2[t * 256 + i];
    out[OFF1 + 9 + t] = ns;
    out[OFF2 + 9 + t] = nc1;
    out[OFF2 + 18 + t] = nc2;
    const float s = ns * 64.f;
    const float term1 = (s * nc1) * 1024.f;
    const float term2 = ((9.f * s) * nc2) * nc1;
    const float term3 = (s * 1024.f) * nc2;
    out[OFF3 + 9 + t] = (term1 + term2) + term3;
  }
  if (t == 9) {
    out[OFF1 + 17] = 64.f;
    out[OFF2 + 17] = 256.f;
    out[OFF2 + 26] = 256.f;
    out[OFF3 + 17] = 4563402752.f;
  }
}

extern "C" void kernel_launch(void* const* d_in, const int* in_sizes, int n_in,
                              void* d_out, int out_size, void* d_ws, size_t ws_size,
                              hipStream_t stream) {
  (void)in_sizes; (void)n_in; (void)out_size; (void)ws_size;
  const float* x      = (const float*)d_in[0];
  const float* n1in   = (const float*)d_in[1];
  const float* n2in   = (const float*)d_in[2];
  const float* flin   = (const float*)d_in[3];
  const float* wsconv = (const float*)d_in[4];
  const float* wsbias = (const float*)d_in[5];
  const float* wc1    = (const float*)d_in[6];
  const float* bc1    = (const float*)d_in[7];
  const float* wc2    = (const float*)d_in[8];
  const float* bc2    = (const float*)d_in[9];
  const float* w1     = (const float*)d_in[10];
  const float* bn1    = (const float*)d_in[11];
  const float* w2     = (const float*)d_in[12];
  const float* bn2    = (const float*)d_in[13];
  const float* w3     = (const float*)d_in[14];
  const float* bn3    = (const float*)d_in[15];
  float* out = (float*)d_out;

  // xT hi/lo live in the (not-yet-written) main-out region of d_out
  _Float16* xh = (_Float16*)d_out;
  _Float16* xl = xh + 33554432;

  char* W = (char*)d_ws;
  _Float16* o1h = (_Float16*)(W);
  _Float16* o1l = (_Float16*)(W + 16777216);
  _Float16* o2h = (_Float16*)(W + 33554432);
  _Float16* o2l = (_Float16*)(W + 50331648);
  _Float16* w1f = (_Float16*)(W + 67108864);  // 1,048,576 B
  _Float16* w2f = (_Float16*)(W + 68157440);  // 2,359,296 B
  _Float16* w3f = (_Float16*)(W + 70516736);  // 1,048,576 B
  float* pooled = (float*)(W + 71565312);     // 2,097,152 B
  float* vec1   = (float*)(W + 73662464);
  float* vec2   = (float*)(W + 73695232);
  float* masksP = (float*)(W + 73703424);
  float* mc1    = (float*)(W + 73705472);
  float* mc2    = (float*)(W + 73713664);
  float* s1     = (float*)(W + 73721856);
  float* t1     = (float*)(W + 73722880);
  float* s2     = (float*)(W + 73723904);
  float* t2     = (float*)(W + 73724928);
  float* s3     = (float*)(W + 73725952);
  float* t3     = (float*)(W + 73730048);

  hipLaunchKernelGGL(k_prep, dim3(6414), dim3(256), 0, stream,
                     bn1, bn2, bn3, w1, w2, w3, w1f, w2f, w3f,
                     s1, t1, s2, t2, s3, t3, pooled, vec2);
  hipLaunchKernelGGL(k_xsplit, dim3(64, 16, NN), dim3(256), 0, stream, x, xh, xl, pooled);
  hipLaunchKernelGGL(k_vec1, dim3(NN), dim3(256), 0, stream, pooled, vec1);
  hipLaunchKernelGGL(k_masks, dim3(NN * 64), dim3(256), 0, stream, wsconv, wsbias, pooled, masksP);
  hipLaunchKernelGGL(k_mc1, dim3(NN * PL), dim3(64), 0, stream, wc1, bc1, vec1, mc1);
  hipLaunchKernelGGL(k_gemm1, dim3(32, 2, NN), dim3(256), 0, stream,
                     xh, xl, w1f, s1, t1, mc1, masksP, o1h, o1l);
  hipLaunchKernelGGL(k_vec2, dim3(NN * 32), dim3(256), 0, stream, o1h, o1l, vec2);
  hipLaunchKernelGGL(k_mc2, dim3(NN * PL), dim3(64), 0, stream, wc2, bc2, vec2, mc2);
  hipLaunchKernelGGL(k_gemm2, dim3(32, 2, NN), dim3(256), 0, stream,
                     o1h, o1l, w2f, s2, t2, mc2, masksP, o2h, o2l);
  hipLaunchKernelGGL(k_gemm3, dim3(32, 8, NN), dim3(256), 0, stream,
                     o2h, o2l, w3f, s3, t3, masksP, x, out);
  hipLaunchKernelGGL(k_book, dim3(1), dim3(64), 0, stream,
                     n1in, n2in, flin, masksP, mc1, mc2, out);
}

// Round 4
// 600.313 us; speedup vs baseline: 1.2449x; 1.2449x over previous
//
#include <hip/hip_runtime.h>
#include <cstddef>
#include <cstdint>

#define NN   8
#define CIN  1024
#define PL   256
#define PE   1024
#define HW   4096
#define EPS_ 1e-5f

typedef _Float16 half8 __attribute__((ext_vector_type(8)));
typedef float floatx4 __attribute__((ext_vector_type(4)));

union HU { uint4 u4; half8 h8; };

__device__ inline uint32_t pack2(float v) {
  union { _Float16 f[2]; uint32_t u; } z;
  _Float16 h = (_Float16)v;
  z.f[0] = h;
  z.f[1] = (_Float16)(v - (float)h);
  return z.u;
}

// Output tail offsets (float offsets in d_out)
static const size_t OFF1 = 33554432;
static const size_t OFF2 = OFF1 + 18;
static const size_t OFF3 = OFF2 + 27;

// ============ prep: weight frag-shuffles + bn fold + zero pooled/vec2 ====
__global__ __launch_bounds__(256) void k_prep(
    const float* __restrict__ bn1, const float* __restrict__ bn2,
    const float* __restrict__ bn3, const float* __restrict__ w1,
    const float* __restrict__ w2, const float* __restrict__ w3,
    _Float16* __restrict__ w1f, _Float16* __restrict__ w2f,
    _Float16* __restrict__ w3f,
    float* __restrict__ s1, float* __restrict__ t1,
    float* __restrict__ s2, float* __restrict__ t2,
    float* __restrict__ s3, float* __restrict__ t3,
    float* __restrict__ pooled, float* __restrict__ vec2) {
  unsigned idx = blockIdx.x * 256 + threadIdx.x;
  if (idx < 262144u) {
    int p = idx >> 10, c = idx & 1023;
    float v = w1[idx]; _Float16 h = (_Float16)v;
    int lane = (((c & 31) >> 3) << 4) | (p & 15);
    size_t base = (size_t)(((c >> 5) * 16 + (p >> 4))) * 1024 + lane * 8 + (c & 7);
    w1f[base] = h; w1f[base + 512] = (_Float16)(v - (float)h);
  } else if (idx < 524288u) {
    unsigned i = idx - 262144u;
    int p = i >> 8, c = i & 255;
    float v = w3[i]; _Float16 h = (_Float16)v;
    int lane = (((c & 31) >> 3) << 4) | (p & 15);
    size_t base = (size_t)((c >> 5) * 64 + (p >> 4)) * 1024 + lane * 8 + (c & 7);
    w3f[base] = h; w3f[base + 512] = (_Float16)(v - (float)h);
  } else if (idx < 1114112u) {
    unsigned i = idx - 524288u;
    unsigned p = i / 2304u, rem = i - p * 2304u;
    unsigned c = rem / 9u, tap = rem - c * 9u;
    float v = w2[i]; _Float16 h = (_Float16)v;
    int lane = (((c & 31) >> 3) << 4) | (p & 15);
    size_t base = (size_t)((tap * 8 + (c >> 5)) * 16 + (p >> 4)) * 1024 + lane * 8 + (c & 7);
    w2f[base] = h; w2f[base + 512] = (_Float16)(v - (float)h);
  } else if (idx < 1638400u) {
    pooled[idx - 1114112u] = 0.f;
  } else if (idx < 1640448u) {
    vec2[idx - 1638400u] = 0.f;
  } else if (idx < 1641984u) {
    int i = idx - 1640448u;
    if (i < 256) {
      float g = bn1[i], b = bn1[256 + i], m = bn1[512 + i], v = bn1[768 + i];
      float s = g / sqrtf(v + EPS_);
      s1[i] = s; t1[i] = b - m * s;
    } else if (i < 512) {
      int c = i - 256;
      float g = bn2[c], b = bn2[256 + c], m = bn2[512 + c], v = bn2[768 + c];
      float s = g / sqrtf(v + EPS_);
      s2[c] = s; t2[c] = b - m * s;
    } else {
      int c = i - 512;
      float g = bn3[c], b = bn3[1024 + c], m = bn3[2048 + c], v = bn3[3072 + c];
      float s = g / sqrtf(v + EPS_);
      s3[c] = s; t3[c] = b - m * s;
    }
  }
}

// ============ x -> transposed fp16 hi/lo split + fused 8x8 pooling =======
__global__ __launch_bounds__(256) void k_xsplit(const float* __restrict__ x,
                                                _Float16* __restrict__ xh,
                                                _Float16* __restrict__ xl,
                                                float* __restrict__ pooled) {
  const int bx = blockIdx.x;  // image row 0..63
  const int hw0 = bx * 64, c0 = blockIdx.y * 64, n = blockIdx.z;
  const int t = threadIdx.x;
  __shared__ float Tt[64][65];
#pragma unroll
  for (int j = 0; j < 4; ++j) {
    int rc = (t >> 4) + j * 16;
    int col = (t & 15) * 4;
    float4 v = *(const float4*)(x + ((size_t)(n * 1024) + c0 + rc) * 4096 + hw0 + col);
    Tt[col + 0][rc] = v.x; Tt[col + 1][rc] = v.y;
    Tt[col + 2][rc] = v.z; Tt[col + 3][rc] = v.w;
  }
  __syncthreads();
  {
    const int ch = t & 63, grp = t >> 6;
    const int pr = bx >> 3;
#pragma unroll
    for (int cc = 0; cc < 2; ++cc) {
      int pc = grp * 2 + cc;
      float s = 0.f;
#pragma unroll
      for (int px = 0; px < 8; ++px) s += Tt[pc * 8 + px][ch];
      atomicAdd(&pooled[(size_t)(n * 64 + pr * 8 + pc) * 1024 + c0 + ch], s * (1.f / 64.f));
    }
  }
  const int hwl = t >> 2, part = t & 3;
  size_t ob = ((size_t)(n * 4096) + hw0 + hwl) * 1024 + c0 + part * 16;
#pragma unroll
  for (int k2 = 0; k2 < 2; ++k2) {
    half8 vh, vl;
#pragma unroll
    for (int e = 0; e < 8; ++e) {
      float v = Tt[hwl][part * 16 + k2 * 8 + e];
      _Float16 hh = (_Float16)v;
      vh[e] = hh; vl[e] = (_Float16)(v - (float)hh);
    }
    *(half8*)(xh + ob + k2 * 8) = vh;
    *(half8*)(xl + ob + k2 * 8) = vl;
  }
}

// ============ vec1 from pooled ===========================================
__global__ __launch_bounds__(256) void k_vec1(const float* __restrict__ pooled,
                                              float* __restrict__ vec1) {
  const int n = blockIdx.x, t = threadIdx.x;
#pragma unroll
  for (int j = 0; j < 4; ++j) {
    int c = j * 256 + t;
    float s = 0.f;
    for (int cell = 0; cell < 64; ++cell)
      s += pooled[(size_t)(n * 64 + cell) * 1024 + c];
    vec1[n * 1024 + c] = s * (1.f / 64.f);
  }
}

// ============ spatial mask ===============================================
__global__ __launch_bounds__(256) void k_masks(const float* __restrict__ wsconv,
                                               const float* __restrict__ wsbias,
                                               const float* __restrict__ pooled,
                                               float* __restrict__ masks) {
  const int bid = blockIdx.x;
  const int n = bid >> 6, cell = bid & 63, ph = cell >> 3, pw = cell & 7;
  const int tid = threadIdx.x;
  const float* pl = pooled + (size_t)n * 64 * 1024;
  float acc = 0.f;
#pragma unroll
  for (int kh = 0; kh < 3; ++kh) {
    int py = ph + kh - 1;
    if (py < 0 || py > 7) continue;
#pragma unroll
    for (int kw = 0; kw < 3; ++kw) {
      int px = pw + kw - 1;
      if (px < 0 || px > 7) continue;
      float4 pv = *(const float4*)(pl + (size_t)(py * 8 + px) * 1024 + tid * 4);
      int k = kh * 3 + kw;
      acc += pv.x * wsconv[(tid * 4 + 0) * 9 + k] + pv.y * wsconv[(tid * 4 + 1) * 9 + k]
           + pv.z * wsconv[(tid * 4 + 2) * 9 + k] + pv.w * wsconv[(tid * 4 + 3) * 9 + k];
    }
  }
  __shared__ float red[256];
  red[tid] = acc;
  __syncthreads();
  for (int s = 128; s > 0; s >>= 1) {
    if (tid < s) red[tid] += red[tid + s];
    __syncthreads();
  }
  if (tid == 0) masks[n * 64 + cell] = (red[0] + wsbias[0] >= 0.f) ? 1.f : 0.f;
}

// ============ mc1 ========================================================
__global__ __launch_bounds__(64) void k_mc1(const float* __restrict__ wc1,
                                            const float* __restrict__ bc1,
                                            const float* __restrict__ vec1,
                                            float* __restrict__ mc1) {
  const int bx = blockIdx.x;
  const int n = bx >> 8, p = bx & 255;
  const int t = threadIdx.x;
  const float* v = vec1 + n * 1024;
  const float* wr = wc1 + (size_t)p * 1024;
  float acc = 0.f;
#pragma unroll
  for (int j = 0; j < 16; ++j) acc += v[t + 64 * j] * wr[t + 64 * j];
  for (int m = 1; m < 64; m <<= 1) acc += __shfl_xor(acc, m, 64);
  if (t == 0) mc1[n * 256 + p] = (acc + bc1[p] >= 0.f) ? 1.f : 0.f;
}

// ============ conv1: MFMA GEMM, pipelined A-frags + B staging ============
__global__ __launch_bounds__(256, 2) void k_gemm1(
    const _Float16* __restrict__ xh, const _Float16* __restrict__ xl,
    const _Float16* __restrict__ w1f,
    const float* __restrict__ s1, const float* __restrict__ t1,
    const float* __restrict__ mc1, const float* __restrict__ masks,
    _Float16* __restrict__ o1h, _Float16* __restrict__ o1l) {
  const int hw0 = blockIdx.x * 128, p0 = blockIdx.y * 128, n = blockIdx.z;
  const int t = threadIdx.x;
  const int lane = t & 63, w = t >> 6;
  const int l15 = lane & 15, l4 = lane >> 4;
  const int wr = w >> 1, wc = w & 1;
  __shared__ __align__(16) char smem[33792];
  _Float16* LB = (_Float16*)smem;  // Bh 0, Bl 5120 (halfs)
  floatx4 acc[4][4] = {};
  const size_t nb = (size_t)(n * 4096) + hw0;
  const _Float16* wfp = w1f + (size_t)((p0 >> 4) + wr * 4) * 1024 + lane * 8;
  const int uk = t >> 9 ? 1 : 0;  // kind for staging role
  const int urow = (t & 511) >> 2, uq = t & 3;  // unused; roles below

  half8 tmpP[4], ahP[4], alP[4];
  // preload kc=0
#pragma unroll
  for (int j = 0; j < 4; ++j) {
    int u = t + 256 * j;
    int kind = u >> 9, rem = u & 511, row = rem >> 2, q = rem & 3;
    tmpP[j] = *(const half8*)((kind ? xl : xh) + (nb + row) * 1024 + q * 8);
  }
#pragma unroll
  for (int i = 0; i < 4; ++i) {
    const _Float16* ap = wfp + (size_t)i * 1024;
    ahP[i] = *(const half8*)ap;
    alP[i] = *(const half8*)(ap + 512);
  }
  (void)uk; (void)urow; (void)uq;
#pragma unroll 1
  for (int kc = 0; kc < 32; ++kc) {
    __syncthreads();   // prior chunk's LDS reads done
#pragma unroll
    for (int j = 0; j < 4; ++j) {
      int u = t + 256 * j;
      int kind = u >> 9, rem = u & 511, row = rem >> 2, q = rem & 3;
      *(half8*)(LB + kind * 5120 + row * 40 + q * 8) = tmpP[j];
    }
    __syncthreads();
    half8 ah[4], al[4];
#pragma unroll
    for (int i = 0; i < 4; ++i) { ah[i] = ahP[i]; al[i] = alP[i]; }
    if (kc < 31) {
      const int c1 = (kc + 1) * 32;
#pragma unroll
      for (int j = 0; j < 4; ++j) {
        int u = t + 256 * j;
        int kind = u >> 9, rem = u & 511, row = rem >> 2, q = rem & 3;
        tmpP[j] = *(const half8*)((kind ? xl : xh) + (nb + row) * 1024 + c1 + q * 8);
      }
#pragma unroll
      for (int i = 0; i < 4; ++i) {
        const _Float16* ap = wfp + (size_t)((kc + 1) * 16 + i) * 1024;
        ahP[i] = *(const half8*)ap;
        alP[i] = *(const half8*)(ap + 512);
      }
    }
    half8 bh[4], bl[4];
#pragma unroll
    for (int j = 0; j < 4; ++j) {
      int r = (wc * 64 + j * 16 + l15) * 40 + l4 * 8;
      bh[j] = *(const half8*)(LB + r);
      bl[j] = *(const half8*)(LB + 5120 + r);
    }
#pragma unroll
    for (int i = 0; i < 4; ++i)
#pragma unroll
      for (int j = 0; j < 4; ++j) {
        acc[i][j] = __builtin_amdgcn_mfma_f32_16x16x32_f16(ah[i], bh[j], acc[i][j], 0, 0, 0);
        acc[i][j] = __builtin_amdgcn_mfma_f32_16x16x32_f16(ah[i], bl[j], acc[i][j], 0, 0, 0);
        acc[i][j] = __builtin_amdgcn_mfma_f32_16x16x32_f16(al[i], bh[j], acc[i][j], 0, 0, 0);
      }
  }
  uint32_t (*T)[132] = (uint32_t(*)[132])smem;
  const int n64 = n * 64;
  const float* mc1n = mc1 + n * 256;
  for (int h = 0; h < 2; ++h) {
    __syncthreads();
    if (wc == h) {
#pragma unroll
      for (int j = 0; j < 4; ++j) {
        int nl = j * 16 + l15;
        int pix = hw0 + h * 64 + nl;
        float msk = masks[n64 + ((pix >> 9) << 3) + ((pix & 63) >> 3)];
#pragma unroll
        for (int i = 0; i < 4; ++i) {
          uint32_t pk[4];
#pragma unroll
          for (int r = 0; r < 4; ++r) {
            int m = wr * 64 + i * 16 + l4 * 4 + r;
            int p = p0 + m;
            float val = fmaxf(fmaf(acc[i][j][r], s1[p], t1[p]), 0.f) * (mc1n[p] * msk);
            pk[r] = pack2(val);
          }
          *(uint4*)&T[nl][wr * 64 + i * 16 + l4 * 4] = *(uint4*)pk;
        }
      }
    }
    __syncthreads();
    {
      int row = t >> 2, seg = t & 3;
      int pix = hw0 + h * 64 + row;
      _Float16* dh = o1h + ((size_t)(n * 4096) + pix) * 256 + p0 + seg * 32;
      _Float16* dl = o1l + ((size_t)(n * 4096) + pix) * 256 + p0 + seg * 32;
#pragma unroll
      for (int k2 = 0; k2 < 4; ++k2) {
        uint4 a = *(uint4*)&T[row][seg * 32 + k2 * 8];
        uint4 b = *(uint4*)&T[row][seg * 32 + k2 * 8 + 4];
        uint4 hv = make_uint4((a.x & 0xFFFFu) | (a.y << 16), (a.z & 0xFFFFu) | (a.w << 16),
                              (b.x & 0xFFFFu) | (b.y << 16), (b.z & 0xFFFFu) | (b.w << 16));
        uint4 lv = make_uint4((a.x >> 16) | (a.y & 0xFFFF0000u), (a.z >> 16) | (a.w & 0xFFFF0000u),
                              (b.x >> 16) | (b.y & 0xFFFF0000u), (b.z >> 16) | (b.w & 0xFFFF0000u));
        *(uint4*)(dh + k2 * 8) = hv;
        *(uint4*)(dl + k2 * 8) = lv;
      }
    }
  }
}

// ============ vec2 =======================================================
__global__ __launch_bounds__(256) void k_vec2(const _Float16* __restrict__ o1h,
                                              const _Float16* __restrict__ o1l,
                                              float* __restrict__ vec2) {
  const int n = blockIdx.x >> 5, ch = blockIdx.x & 31;
  const int t = threadIdx.x;
  const _Float16* bh = o1h + ((size_t)(n * 4096) + ch * 128) * 256 + t;
  const _Float16* bl = o1l + ((size_t)(n * 4096) + ch * 128) * 256 + t;
  float s = 0.f;
  for (int i = 0; i < 128; ++i)
    s += (float)bh[(size_t)i * 256] + (float)bl[(size_t)i * 256];
  atomicAdd(&vec2[n * 256 + t], s * (1.f / 4096.f));
}

// ============ mc2 ========================================================
__global__ __launch_bounds__(64) void k_mc2(const float* __restrict__ wc2,
                                            const float* __restrict__ bc2,
                                            const float* __restrict__ vec2,
                                            float* __restrict__ mc2) {
  const int bx = blockIdx.x;
  const int n = bx >> 8, p = bx & 255;
  const int t = threadIdx.x;
  const float* v = vec2 + n * 256;
  const float* wr = wc2 + (size_t)p * 256;
  float acc = 0.f;
#pragma unroll
  for (int j = 0; j < 4; ++j) acc += v[t + 64 * j] * wr[t + 64 * j];
  for (int m = 1; m < 64; m <<= 1) acc += __shfl_xor(acc, m, 64);
  if (t == 0) mc2[n * 256 + p] = (acc + bc2[p] >= 0.f) ? 1.f : 0.f;
}

// ============ conv2: 3x3 MFMA, strip LDS, pipelined A-frags + strip ======
__global__ __launch_bounds__(256, 2) void k_gemm2(
    const _Float16* __restrict__ o1h, const _Float16* __restrict__ o1l,
    const _Float16* __restrict__ w2f,
    const float* __restrict__ s2, const float* __restrict__ t2,
    const float* __restrict__ mc2, const float* __restrict__ masks,
    _Float16* __restrict__ o2h, _Float16* __restrict__ o2l) {
  const int bt = blockIdx.x, p0 = blockIdx.y * 128, n = blockIdx.z;
  const int hw0 = bt * 128;
  const int t = threadIdx.x;
  const int lane = t & 63, w = t >> 6;
  const int l15 = lane & 15, l4 = lane >> 4;
  const int wr = w >> 1, wc = w & 1;
  __shared__ __align__(16) char smem[42240];
  _Float16* LB = (_Float16*)smem;
  floatx4 acc[4][4] = {};
  const size_t onb = (size_t)(n * 4096);
  const int row0 = bt * 2 - 1;
  const _Float16* wfp = w2f + (size_t)((p0 >> 4) + wr * 4) * 1024 + lane * 8;

  HU st[9];
  half8 ahP[4], alP[4];

  // ---- strip load (to regs) for chunk kc ----
  auto load_strip = [&](int kc) {
    const int c0 = kc * 32;
#pragma unroll
    for (int j2 = 0; j2 < 9; ++j2) {
      int u = t + 256 * j2;
      st[j2].u4 = make_uint4(0u, 0u, 0u, 0u);
      if (u < 2112) {
        int kind = (u >= 1056) ? 1 : 0;
        int rem = u - kind * 1056;
        int pix = rem >> 2, q = rem & 3;
        int sr = pix / 66, sc = pix - sr * 66;
        int gr = row0 + sr, gc = sc - 1;
        if (gr >= 0 && gr < 64 && gc >= 0 && gc < 64) {
          const _Float16* src = (kind ? o1l : o1h) + (onb + gr * 64 + gc) * 256 + c0 + q * 8;
          st[j2].h8 = *(const half8*)src;
        }
      }
    }
  };
  auto write_strip = [&]() {
#pragma unroll
    for (int j2 = 0; j2 < 9; ++j2) {
      int u = t + 256 * j2;
      if (u < 2112) {
        int kind = (u >= 1056) ? 1 : 0;
        int rem = u - kind * 1056;
        int pix = rem >> 2, q = rem & 3;
        *(half8*)(LB + kind * 10560 + pix * 40 + q * 8) = st[j2].h8;
      }
    }
  };
  auto loadA = [&](int tap, int kc) {
#pragma unroll
    for (int i = 0; i < 4; ++i) {
      const _Float16* ap = wfp + (size_t)(((tap * 8 + kc) * 16) + i) * 1024;
      ahP[i] = *(const half8*)ap;
      alP[i] = *(const half8*)(ap + 512);
    }
  };

  load_strip(0);
  write_strip();
  loadA(0, 0);
  __syncthreads();
#pragma unroll 1
  for (int kc = 0; kc < 8; ++kc) {
    if (kc < 7) load_strip(kc + 1);   // in-flight across the tap loop
#pragma unroll
    for (int tap = 0; tap < 9; ++tap) {
      half8 ah[4], al[4];
#pragma unroll
      for (int i = 0; i < 4; ++i) { ah[i] = ahP[i]; al[i] = alP[i]; }
      if (tap < 8) loadA(tap + 1, kc);
      else if (kc < 7) loadA(0, kc + 1);
      const int kh = tap / 3, kw = tap - kh * 3;
      half8 bh[4], bl[4];
#pragma unroll
      for (int j = 0; j < 4; ++j) {
        int pi = (wc + kh) * 66 + j * 16 + l15 + kw;
        bh[j] = *(const half8*)(LB + pi * 40 + l4 * 8);
        bl[j] = *(const half8*)(LB + 10560 + pi * 40 + l4 * 8);
      }
#pragma unroll
      for (int i = 0; i < 4; ++i)
#pragma unroll
        for (int j = 0; j < 4; ++j) {
          acc[i][j] = __builtin_amdgcn_mfma_f32_16x16x32_f16(ah[i], bh[j], acc[i][j], 0, 0, 0);
          acc[i][j] = __builtin_amdgcn_mfma_f32_16x16x32_f16(ah[i], bl[j], acc[i][j], 0, 0, 0);
          acc[i][j] = __builtin_amdgcn_mfma_f32_16x16x32_f16(al[i], bh[j], acc[i][j], 0, 0, 0);
        }
    }
    if (kc < 7) {
      __syncthreads();   // strip reads of this chunk done
      write_strip();
      __syncthreads();
    }
  }
  uint32_t (*T)[132] = (uint32_t(*)[132])smem;
  const int n64 = n * 64;
  const float* mc2n = mc2 + n * 256;
  for (int h = 0; h < 2; ++h) {
    __syncthreads();
    if (wc == h) {
#pragma unroll
      for (int j = 0; j < 4; ++j) {
        int nl = j * 16 + l15;
        int pix = hw0 + h * 64 + nl;
        float msk = masks[n64 + ((pix >> 9) << 3) + ((pix & 63) >> 3)];
#pragma unroll
        for (int i = 0; i < 4; ++i) {
          uint32_t pk[4];
#pragma unroll
          for (int r = 0; r < 4; ++r) {
            int m = wr * 64 + i * 16 + l4 * 4 + r;
            int p = p0 + m;
            float val = fmaxf(fmaf(acc[i][j][r], s2[p], t2[p]), 0.f) * (mc2n[p] * msk);
            pk[r] = pack2(val);
          }
          *(uint4*)&T[nl][wr * 64 + i * 16 + l4 * 4] = *(uint4*)pk;
        }
      }
    }
    __syncthreads();
    {
      int row = t >> 2, seg = t & 3;
      int pix = hw0 + h * 64 + row;
      _Float16* dh = o2h + ((size_t)(n * 4096) + pix) * 256 + p0 + seg * 32;
      _Float16* dl = o2l + ((size_t)(n * 4096) + pix) * 256 + p0 + seg * 32;
#pragma unroll
      for (int k2 = 0; k2 < 4; ++k2) {
        uint4 a = *(uint4*)&T[row][seg * 32 + k2 * 8];
        uint4 b = *(uint4*)&T[row][seg * 32 + k2 * 8 + 4];
        uint4 hv = make_uint4((a.x & 0xFFFFu) | (a.y << 16), (a.z & 0xFFFFu) | (a.w << 16),
                              (b.x & 0xFFFFu) | (b.y << 16), (b.z & 0xFFFFu) | (b.w << 16));
        uint4 lv = make_uint4((a.x >> 16) | (a.y & 0xFFFF0000u), (a.z >> 16) | (a.w & 0xFFFF0000u),
                              (b.x >> 16) | (b.y & 0xFFFF0000u), (b.z >> 16) | (b.w & 0xFFFF0000u));
        *(uint4*)(dh + k2 * 8) = hv;
        *(uint4*)(dl + k2 * 8) = lv;
      }
    }
  }
}

// ============ conv3: MFMA GEMM pipelined + bn3*mask + x + relu ===========
__global__ __launch_bounds__(256, 2) void k_gemm3(
    const _Float16* __restrict__ o2h, const _Float16* __restrict__ o2l,
    const _Float16* __restrict__ w3f,
    const float* __restrict__ s3, const float* __restrict__ t3,
    const float* __restrict__ masks, const float* __restrict__ x,
    float* __restrict__ out) {
  const int hw0 = blockIdx.x * 128, p0 = blockIdx.y * 128, n = blockIdx.z;
  const int t = threadIdx.x;
  const int lane = t & 63, w = t >> 6;
  const int l15 = lane & 15, l4 = lane >> 4;
  const int wr = w >> 1, wc = w & 1;
  __shared__ __align__(16) char smem[20480];
  _Float16* LB = (_Float16*)smem;
  floatx4 acc[4][4] = {};
  const size_t nb = (size_t)(n * 4096) + hw0;
  const _Float16* wfp = w3f + (size_t)((p0 >> 4) + wr * 4) * 1024 + lane * 8;

  half8 tmpP[4], ahP[4], alP[4];
#pragma unroll
  for (int j = 0; j < 4; ++j) {
    int u = t + 256 * j;
    int kind = u >> 9, rem = u & 511, row = rem >> 2, q = rem & 3;
    tmpP[j] = *(const half8*)((kind ? o2l : o2h) + (nb + row) * 256 + q * 8);
  }
#pragma unroll
  for (int i = 0; i < 4; ++i) {
    const _Float16* ap = wfp + (size_t)i * 1024;
    ahP[i] = *(const half8*)ap;
    alP[i] = *(const half8*)(ap + 512);
  }
#pragma unroll 1
  for (int kc = 0; kc < 8; ++kc) {
    __syncthreads();
#pragma unroll
    for (int j = 0; j < 4; ++j) {
      int u = t + 256 * j;
      int kind = u >> 9, rem = u & 511, row = rem >> 2, q = rem & 3;
      *(half8*)(LB + kind * 5120 + row * 40 + q * 8) = tmpP[j];
    }
    __syncthreads();
    half8 ah[4], al[4];
#pragma unroll
    for (int i = 0; i < 4; ++i) { ah[i] = ahP[i]; al[i] = alP[i]; }
    if (kc < 7) {
      const int c1 = (kc + 1) * 32;
#pragma unroll
      for (int j = 0; j < 4; ++j) {
        int u = t + 256 * j;
        int kind = u >> 9, rem = u & 511, row = rem >> 2, q = rem & 3;
        tmpP[j] = *(const half8*)((kind ? o2l : o2h) + (nb + row) * 256 + c1 + q * 8);
      }
#pragma unroll
      for (int i = 0; i < 4; ++i) {
        const _Float16* ap = wfp + (size_t)((kc + 1) * 64 + i) * 1024;
        ahP[i] = *(const half8*)ap;
        alP[i] = *(const half8*)(ap + 512);
      }
    }
    half8 bh[4], bl[4];
#pragma unroll
    for (int j = 0; j < 4; ++j) {
      int r = (wc * 64 + j * 16 + l15) * 40 + l4 * 8;
      bh[j] = *(const half8*)(LB + r);
      bl[j] = *(const half8*)(LB + 5120 + r);
    }
#pragma unroll
    for (int i = 0; i < 4; ++i)
#pragma unroll
      for (int j = 0; j < 4; ++j) {
        acc[i][j] = __builtin_amdgcn_mfma_f32_16x16x32_f16(ah[i], bh[j], acc[i][j], 0, 0, 0);
        acc[i][j] = __builtin_amdgcn_mfma_f32_16x16x32_f16(ah[i], bl[j], acc[i][j], 0, 0, 0);
        acc[i][j] = __builtin_amdgcn_mfma_f32_16x16x32_f16(al[i], bh[j], acc[i][j], 0, 0, 0);
      }
  }
  const int n64 = n * 64;
  float msk[4];
#pragma unroll
  for (int j = 0; j < 4; ++j) {
    int pix = hw0 + wc * 64 + j * 16 + l15;
    msk[j] = masks[n64 + ((pix >> 9) << 3) + ((pix & 63) >> 3)];
  }
#pragma unroll
  for (int i = 0; i < 4; ++i)
#pragma unroll
    for (int r = 0; r < 4; ++r) {
      int m = wr * 64 + i * 16 + l4 * 4 + r;
      int pe = p0 + m;
      float sc = s3[pe], sh = t3[pe];
      size_t rowoff = ((size_t)(n * 1024) + pe) * 4096 + hw0;
#pragma unroll
      for (int j = 0; j < 4; ++j) {
        int nl = wc * 64 + j * 16 + l15;
        float val = fmaf(acc[i][j][r], sc, sh) * msk[j];
        size_t off = rowoff + nl;
        out[off] = fmaxf(val + x[off], 0.f);
      }
    }
}

// ============ bookkeeping ================================================
__global__ __launch_bounds__(64) void k_book(const float* __restrict__ n1in,
                                             const float* __restrict__ n2in,
                                             const float* __restrict__ flin,
                                             const float* __restrict__ masks,
                                             const float* __restrict__ mc1,
                                             const float* __restrict__ mc2,
                                             float* __restrict__ out) {
  const int t = threadIdx.x;
  if (t < 9) {
    out[OFF1 + t] = n1in[t];
    out[OFF2 + t] = n2in[t];
    out[OFF3 + t] = flin[t];
  }
  if (t < 8) {
    float ns = 0.f, nc1 = 0.f, nc2 = 0.f;
    for (int i = 0; i < 64; ++i) ns += masks[t * 64 + i];
    for (int i = 0; i < 256; ++i) nc1 += mc1[t * 256 + i];
    for (int i = 0; i < 256; ++i) nc2 += mc2[t * 256 + i];
    out[OFF1 + 9 + t] = ns;
    out[OFF2 + 9 + t] = nc1;
    out[OFF2 + 18 + t] = nc2;
    const float s = ns * 64.f;
    const float term1 = (s * nc1) * 1024.f;
    const float term2 = ((9.f * s) * nc2) * nc1;
    const float term3 = (s * 1024.f) * nc2;
    out[OFF3 + 9 + t] = (term1 + term2) + term3;
  }
  if (t == 9) {
    out[OFF1 + 17] = 64.f;
    out[OFF2 + 17] = 256.f;
    out[OFF2 + 26] = 256.f;
    out[OFF3 + 17] = 4563402752.f;
  }
}

extern "C" void kernel_launch(void* const* d_in, const int* in_sizes, int n_in,
                              void* d_out, int out_size, void* d_ws, size_t ws_size,
                              hipStream_t stream) {
  (void)in_sizes; (void)n_in; (void)out_size; (void)ws_size;
  const float* x      = (const float*)d_in[0];
  const float* n1in   = (const float*)d_in[1];
  const float* n2in   = (const float*)d_in[2];
  const float* flin   = (const float*)d_in[3];
  const float* wsconv = (const float*)d_in[4];
  const float* wsbias = (const float*)d_in[5];
  const float* wc1    = (const float*)d_in[6];
  const float* bc1    = (const float*)d_in[7];
  const float* wc2    = (const float*)d_in[8];
  const float* bc2    = (const float*)d_in[9];
  const float* w1     = (const float*)d_in[10];
  const float* bn1    = (const float*)d_in[11];
  const float* w2     = (const float*)d_in[12];
  const float* bn2    = (const float*)d_in[13];
  const float* w3     = (const float*)d_in[14];
  const float* bn3    = (const float*)d_in[15];
  float* out = (float*)d_out;

  _Float16* xh = (_Float16*)d_out;
  _Float16* xl = xh + 33554432;

  char* W = (char*)d_ws;
  _Float16* o1h = (_Float16*)(W);
  _Float16* o1l = (_Float16*)(W + 16777216);
  _Float16* o2h = (_Float16*)(W + 33554432);
  _Float16* o2l = (_Float16*)(W + 50331648);
  _Float16* w1f = (_Float16*)(W + 67108864);
  _Float16* w2f = (_Float16*)(W + 68157440);
  _Float16* w3f = (_Float16*)(W + 70516736);
  float* pooled = (float*)(W + 71565312);
  float* vec1   = (float*)(W + 73662464);
  float* vec2   = (float*)(W + 73695232);
  float* masksP = (float*)(W + 73703424);
  float* mc1    = (float*)(W + 73705472);
  float* mc2    = (float*)(W + 73713664);
  float* s1     = (float*)(W + 73721856);
  float* t1     = (float*)(W + 73722880);
  float* s2     = (float*)(W + 73723904);
  float* t2     = (float*)(W + 73724928);
  float* s3     = (float*)(W + 73725952);
  float* t3     = (float*)(W + 73730048);

  hipLaunchKernelGGL(k_prep, dim3(6414), dim3(256), 0, stream,
                     bn1, bn2, bn3, w1, w2, w3, w1f, w2f, w3f,
                     s1, t1, s2, t2, s3, t3, pooled, vec2);
  hipLaunchKernelGGL(k_xsplit, dim3(64, 16, NN), dim3(256), 0, stream, x, xh, xl, pooled);
  hipLaunchKernelGGL(k_vec1, dim3(NN), dim3(256), 0, stream, pooled, vec1);
  hipLaunchKernelGGL(k_masks, dim3(NN * 64), dim3(256), 0, stream, wsconv, wsbias, pooled, masksP);
  hipLaunchKernelGGL(k_mc1, dim3(NN * PL), dim3(64), 0, stream, wc1, bc1, vec1, mc1);
  hipLaunchKernelGGL(k_gemm1, dim3(32, 2, NN), dim3(256), 0, stream,
                     xh, xl, w1f, s1, t1, mc1, masksP, o1h, o1l);
  hipLaunchKernelGGL(k_vec2, dim3(NN * 32), dim3(256), 0, stream, o1h, o1l, vec2);
  hipLaunchKernelGGL(k_mc2, dim3(NN * PL), dim3(64), 0, stream, wc2, bc2, vec2, mc2);
  hipLaunchKernelGGL(k_gemm2, dim3(32, 2, NN), dim3(256), 0, stream,
                     o1h, o1l, w2f, s2, t2, mc2, masksP, o2h, o2l);
  hipLaunchKernelGGL(k_gemm3, dim3(32, 8, NN), dim3(256), 0, stream,
                     o2h, o2l, w3f, s3, t3, masksP, x, out);
  hipLaunchKernelGGL(k_book, dim3(1), dim3(64), 0, stream,
                     n1in, n2in, flin, masksP, mc1, mc2, out);
}